// Round 1
// baseline (169.807 us; speedup 1.0000x reference)
//
#include <hip/hip_runtime.h>
#include <hip/hip_bf16.h>
#include <stdint.h>

using int32x4 = __attribute__((ext_vector_type(4))) int;

#define DIN 2048
#define DOUT 2048
#define NTOK 16384
#define KDIM 2048
#define NDIM 2048

#define BM 128
#define BN 128
#define BK 64

typedef const __attribute__((address_space(1))) void* gp_t;
typedef __attribute__((address_space(3))) void* lp_t;

__device__ __forceinline__ void gload16(const void* g, void* l) {
    __builtin_amdgcn_global_load_lds((gp_t)g, (lp_t)l, 16, 0, 0);
}

// ---------------- Kernel 0: ternary int32 -> int8 ----------------
__global__ __launch_bounds__(256) void k_wconv(const int* __restrict__ wt,
                                               signed char* __restrict__ w8) {
    int i = blockIdx.x * 256 + threadIdx.x;
    int4 v = ((const int4*)wt)[i];
    char4 c;
    c.x = (signed char)v.x; c.y = (signed char)v.y;
    c.z = (signed char)v.z; c.w = (signed char)v.w;
    ((char4*)w8)[i] = c;
}

// ---------------- Kernel 1: LayerNorm + int8 absmax quant ----------------
__global__ __launch_bounds__(256) void k_lnq(const float* __restrict__ x,
                                             signed char* __restrict__ xq,
                                             float* __restrict__ xscale) {
    __shared__ float sm[12];
    const int row = blockIdx.x;
    const int tid = threadIdx.x;
    const float* p = x + (size_t)row * DIN;
    const float4 v0 = ((const float4*)p)[tid * 2];
    const float4 v1 = ((const float4*)p)[tid * 2 + 1];
    float vv[8] = {v0.x, v0.y, v0.z, v0.w, v1.x, v1.y, v1.z, v1.w};
    float s = 0.f, ss = 0.f;
#pragma unroll
    for (int i = 0; i < 8; i++) { s += vv[i]; ss += vv[i] * vv[i]; }
#pragma unroll
    for (int o = 32; o; o >>= 1) { s += __shfl_down(s, o); ss += __shfl_down(ss, o); }
    const int wv = tid >> 6;
    if ((tid & 63) == 0) { sm[wv] = s; sm[4 + wv] = ss; }
    __syncthreads();
    s = sm[0] + sm[1] + sm[2] + sm[3];
    ss = sm[4] + sm[5] + sm[6] + sm[7];
    const float mu = s * (1.f / DIN);
    const float var = ss * (1.f / DIN) - mu * mu;
    const float rstd = 1.f / sqrtf(var + 1e-5f);
    float am = 0.f;
#pragma unroll
    for (int i = 0; i < 8; i++) am = fmaxf(am, fabsf(vv[i] - mu));
#pragma unroll
    for (int o = 32; o; o >>= 1) am = fmaxf(am, __shfl_down(am, o));
    __syncthreads();  // sm reuse
    if ((tid & 63) == 0) sm[8 + wv] = am;
    __syncthreads();
    am = fmaxf(fmaxf(sm[8], sm[9]), fmaxf(sm[10], sm[11]));
    const float scale = fmaxf(am * rstd, 1e-5f) * (1.f / 127.f);
    union { signed char c[8]; int2 v; } u;
#pragma unroll
    for (int i = 0; i < 8; i++) {
        float xn = (vv[i] - mu) * rstd;
        float t = rintf(xn / scale);
        t = fminf(127.f, fmaxf(-127.f, t));
        u.c[i] = (signed char)t;
    }
    ((int2*)(xq + (size_t)row * DIN))[tid] = u.v;
    if (tid == 0) xscale[row] = scale;
}

// ---------------- Kernel 2: int8 MFMA GEMM, fp32 scaled epilogue ----------------
// A: [M, K] int8 (quantized activations), B: [N, K] int8 (ternary weights)
// C[m,n] = (sum_k A[m,k]*B[n,k]) * xs[m] * wsc[n]
__global__ __launch_bounds__(256) void k_gemm(const signed char* __restrict__ A,
                                              const signed char* __restrict__ B,
                                              const float* __restrict__ xs,
                                              const float* __restrict__ wsc,
                                              float* __restrict__ C) {
    __shared__ __align__(16) signed char la[BM * BK];
    __shared__ __align__(16) signed char lb[BN * BK];
    __shared__ float s_xs[BM];
    __shared__ float s_ws[BN];

    const int tid = threadIdx.x;
    // XCD-aware swizzle (gridDim.x = 2048, divisible by 8 -> bijective)
    const int nblk = gridDim.x;
    const int cpx = nblk >> 3;
    int bid = (blockIdx.x & 7) * cpx + (blockIdx.x >> 3);
    const int nbn = NDIM / BN;  // 16
    const int bm = bid / nbn, bn = bid % nbn;

    if (tid < BM) s_xs[tid] = xs[bm * BM + tid];
    if (tid < BN) s_ws[tid] = wsc[bn * BN + tid];

    const int lane = tid & 63;
    const int wave = tid >> 6;
    const int wr = (wave >> 1) * 64;  // wave row offset in tile
    const int wc = (wave & 1) * 64;   // wave col offset in tile

    // staging: each thread loads 16B; tile is [128][64] bytes, linear
    const int sr = tid >> 2;            // 0..63
    const int scol = (tid & 3) * 16;    // byte col within row
    const signed char* ga = A + (size_t)(bm * BM + sr) * KDIM + scol;
    const signed char* gb = B + (size_t)(bn * BN + sr) * KDIM + scol;

    int32x4 acc[4][4];
#pragma unroll
    for (int i = 0; i < 4; i++)
#pragma unroll
        for (int j = 0; j < 4; j++) {
            int32x4 z = {0, 0, 0, 0};
            acc[i][j] = z;
        }

    const int lrow = lane & 15;
    const int koff = (lane >> 4) * 16;  // byte offset along k

    for (int k0 = 0; k0 < KDIM; k0 += BK) {
        __syncthreads();  // previous compute done before LDS overwrite
        gload16(ga + k0, &la[tid * 16]);
        gload16(ga + (size_t)64 * KDIM + k0, &la[4096 + tid * 16]);
        gload16(gb + k0, &lb[tid * 16]);
        gload16(gb + (size_t)64 * KDIM + k0, &lb[4096 + tid * 16]);
        __syncthreads();  // compiler drains vmcnt(0) before barrier

        int32x4 af[4], bf[4];
#pragma unroll
        for (int i = 0; i < 4; i++)
            af[i] = *(const int32x4*)&la[(wr + i * 16 + lrow) * BK + koff];
#pragma unroll
        for (int j = 0; j < 4; j++)
            bf[j] = *(const int32x4*)&lb[(wc + j * 16 + lrow) * BK + koff];
#pragma unroll
        for (int i = 0; i < 4; i++)
#pragma unroll
            for (int j = 0; j < 4; j++)
                acc[i][j] = __builtin_amdgcn_mfma_i32_16x16x64_i8(af[i], bf[j], acc[i][j], 0, 0, 0);
    }

    // epilogue: C/D layout col = lane&15, row = (lane>>4)*4 + reg
    const int col = lane & 15;
    const int r0 = (lane >> 4) * 4;
#pragma unroll
    for (int i = 0; i < 4; i++) {
#pragma unroll
        for (int j = 0; j < 4; j++) {
            const int ln = wc + j * 16 + col;
            const int gn = bn * BN + ln;
            const float wsv = s_ws[ln];
#pragma unroll
            for (int r = 0; r < 4; r++) {
                const int lm = wr + i * 16 + r0 + r;
                const float v = (float)acc[i][j][r] * s_xs[lm] * wsv;
                C[(size_t)(bm * BM + lm) * NDIM + gn] = v;
            }
        }
    }
}

// ---------------- Kernel 3: output LayerNorm (in-place on d_out) ----------------
__global__ __launch_bounds__(256) void k_lnout(float* __restrict__ y) {
    __shared__ float sm[8];
    const int row = blockIdx.x;
    const int tid = threadIdx.x;
    float* p = y + (size_t)row * DOUT;
    float4 v0 = ((float4*)p)[tid * 2];
    float4 v1 = ((float4*)p)[tid * 2 + 1];
    float vv[8] = {v0.x, v0.y, v0.z, v0.w, v1.x, v1.y, v1.z, v1.w};
    float s = 0.f, ss = 0.f;
#pragma unroll
    for (int i = 0; i < 8; i++) { s += vv[i]; ss += vv[i] * vv[i]; }
#pragma unroll
    for (int o = 32; o; o >>= 1) { s += __shfl_down(s, o); ss += __shfl_down(ss, o); }
    const int wv = tid >> 6;
    if ((tid & 63) == 0) { sm[wv] = s; sm[4 + wv] = ss; }
    __syncthreads();
    s = sm[0] + sm[1] + sm[2] + sm[3];
    ss = sm[4] + sm[5] + sm[6] + sm[7];
    const float mu = s * (1.f / DOUT);
    const float var = ss * (1.f / DOUT) - mu * mu;
    const float rstd = 1.f / sqrtf(var + 1e-5f);
#pragma unroll
    for (int i = 0; i < 8; i++) vv[i] = (vv[i] - mu) * rstd;
    float4 o0, o1;
    o0.x = vv[0]; o0.y = vv[1]; o0.z = vv[2]; o0.w = vv[3];
    o1.x = vv[4]; o1.y = vv[5]; o1.z = vv[6]; o1.w = vv[7];
    ((float4*)p)[tid * 2] = o0;
    ((float4*)p)[tid * 2 + 1] = o1;
}

extern "C" void kernel_launch(void* const* d_in, const int* in_sizes, int n_in,
                              void* d_out, int out_size, void* d_ws, size_t ws_size,
                              hipStream_t stream) {
    const float* x = (const float*)d_in[0];
    const int* wt = (const int*)d_in[1];
    const float* wscale = (const float*)d_in[2];
    float* out = (float*)d_out;

    // workspace layout: w8 (4MB) | xq (32MB) | xs (64KB)  -> ~36.1MB
    signed char* w8 = (signed char*)d_ws;
    signed char* xq = (signed char*)d_ws + (size_t)4 * 1024 * 1024;
    float* xs = (float*)((char*)d_ws + (size_t)36 * 1024 * 1024);

    k_wconv<<<(DOUT * DIN / 4) / 256, 256, 0, stream>>>(wt, w8);
    k_lnq<<<NTOK, 256, 0, stream>>>(x, xq, xs);
    k_gemm<<<(NTOK / BM) * (NDIM / BN), 256, 0, stream>>>(xq, w8, xs, wscale, out);
    k_lnout<<<NTOK, 256, 0, stream>>>(out);
}

// Round 2
// 167.214 us; speedup vs baseline: 1.0155x; 1.0155x over previous
//
#include <hip/hip_runtime.h>
#include <hip/hip_bf16.h>
#include <stdint.h>

using int32x4 = __attribute__((ext_vector_type(4))) int;

#define DIN 2048
#define DOUT 2048
#define NTOK 16384
#define KDIM 2048
#define NDIM 2048

#define BM 256
#define BN 256
#define BKB 128           // K-bytes (=elements) staged per tile
#define NKT (KDIM / BKB)  // 16

typedef const __attribute__((address_space(1))) void* gp_t;
typedef __attribute__((address_space(3))) void* lp_t;

__device__ __forceinline__ void gload16(const void* g, void* l) {
    __builtin_amdgcn_global_load_lds((gp_t)g, (lp_t)l, 16, 0, 0);
}

// ---------------- Kernel 0: ternary int32 -> int8 ----------------
__global__ __launch_bounds__(256) void k_wconv(const int* __restrict__ wt,
                                               signed char* __restrict__ w8) {
    int i = blockIdx.x * 256 + threadIdx.x;
    int4 v = ((const int4*)wt)[i];
    char4 c;
    c.x = (signed char)v.x; c.y = (signed char)v.y;
    c.z = (signed char)v.z; c.w = (signed char)v.w;
    ((char4*)w8)[i] = c;
}

// ---------------- Kernel 1: LayerNorm + int8 absmax quant ----------------
__global__ __launch_bounds__(256) void k_lnq(const float* __restrict__ x,
                                             signed char* __restrict__ xq,
                                             float* __restrict__ xscale) {
    __shared__ float sm[12];
    const int row = blockIdx.x;
    const int tid = threadIdx.x;
    const float* p = x + (size_t)row * DIN;
    const float4 v0 = ((const float4*)p)[tid * 2];
    const float4 v1 = ((const float4*)p)[tid * 2 + 1];
    float vv[8] = {v0.x, v0.y, v0.z, v0.w, v1.x, v1.y, v1.z, v1.w};
    float s = 0.f, ss = 0.f;
#pragma unroll
    for (int i = 0; i < 8; i++) { s += vv[i]; ss += vv[i] * vv[i]; }
#pragma unroll
    for (int o = 32; o; o >>= 1) { s += __shfl_down(s, o); ss += __shfl_down(ss, o); }
    const int wv = tid >> 6;
    if ((tid & 63) == 0) { sm[wv] = s; sm[4 + wv] = ss; }
    __syncthreads();
    s = sm[0] + sm[1] + sm[2] + sm[3];
    ss = sm[4] + sm[5] + sm[6] + sm[7];
    const float mu = s * (1.f / DIN);
    const float var = ss * (1.f / DIN) - mu * mu;
    const float rstd = 1.f / sqrtf(var + 1e-5f);
    float am = 0.f;
#pragma unroll
    for (int i = 0; i < 8; i++) am = fmaxf(am, fabsf(vv[i] - mu));
#pragma unroll
    for (int o = 32; o; o >>= 1) am = fmaxf(am, __shfl_down(am, o));
    __syncthreads();
    if ((tid & 63) == 0) sm[8 + wv] = am;
    __syncthreads();
    am = fmaxf(fmaxf(sm[8], sm[9]), fmaxf(sm[10], sm[11]));
    const float scale = fmaxf(am * rstd, 1e-5f) * (1.f / 127.f);
    union { signed char c[8]; int2 v; } u;
#pragma unroll
    for (int i = 0; i < 8; i++) {
        float xn = (vv[i] - mu) * rstd;
        float t = rintf(xn / scale);
        t = fminf(127.f, fmaxf(-127.f, t));
        u.c[i] = (signed char)t;
    }
    ((int2*)(xq + (size_t)row * DIN))[tid] = u.v;
    if (tid == 0) xscale[row] = scale;
}

// ---------------- Kernel 2: 256x256 8-phase i8 MFMA GEMM ----------------
// A: [M,K] int8, B: [N,K] int8; C[m,n] = dot * xs[m] * wsc[n]
#define MFMA4(I, AF) \
    acc[I][0] = __builtin_amdgcn_mfma_i32_16x16x64_i8(AF, bf0, acc[I][0], 0, 0, 0); \
    acc[I][1] = __builtin_amdgcn_mfma_i32_16x16x64_i8(AF, bf1, acc[I][1], 0, 0, 0); \
    acc[I][2] = __builtin_amdgcn_mfma_i32_16x16x64_i8(AF, bf2, acc[I][2], 0, 0, 0); \
    acc[I][3] = __builtin_amdgcn_mfma_i32_16x16x64_i8(AF, bf3, acc[I][3], 0, 0, 0);

__global__ __launch_bounds__(512, 2) void k_gemm(const signed char* __restrict__ A,
                                                 const signed char* __restrict__ B,
                                                 const float* __restrict__ xs,
                                                 const float* __restrict__ wsc,
                                                 float* __restrict__ C) {
    __shared__ __align__(16) signed char lA[2][BM * BKB];  // 64 KB
    __shared__ __align__(16) signed char lB[2][BN * BKB];  // 64 KB
    __shared__ float s_xs[BM];
    __shared__ float s_ws[BN];

    const int tid = threadIdx.x;
    // XCD-aware swizzle; 512 blocks % 8 == 0 -> bijective
    const int orig = blockIdx.x;
    const int bid = (orig & 7) * 64 + (orig >> 3);
    const int bm = bid >> 3;   // 0..63
    const int bn = bid & 7;    // 0..7

    const int lane = tid & 63;
    const int wave = tid >> 6;
    const int wm = wave >> 2;  // 0..1
    const int wn = wave & 3;   // 0..3
    const int lo = lane & 15;
    const int q  = lane >> 4;

    // ---- staging geometry (thread-fixed) ----
    // LDS (row r, chunk c) holds global k-chunk (c ^ (r&7)) of row r.
    const int srow = tid >> 3;           // 0..63
    const int schunk = tid & 7;          // dest 16B chunk within 128B row
    const int gchunk = schunk ^ (srow & 7);
    const signed char* gA = A + (size_t)(bm * BM + srow) * KDIM + gchunk * 16;
    const signed char* gB = B + (size_t)(bn * BN + srow) * KDIM + gchunk * 16;
    const int dst = srow * BKB + schunk * 16;

    // ---- fragment read offsets (swizzled) ----
    const int arow = (wm * 128 + lo) * BKB;
    const int brow = (wn * 64 + lo) * BKB;
    const int ck0 = (q ^ (lane & 7)) * 16;        // ks=0
    const int ck1 = ((4 + q) ^ (lane & 7)) * 16;  // ks=1

    if (tid < 256) s_xs[tid] = xs[bm * BM + tid];
    else           s_ws[tid - 256] = wsc[bn * BN + tid - 256];

    // ---- prologue: stage tile 0 into buf 0 (8 loads) ----
    {
        signed char* la0 = &lA[0][0];
        signed char* lb0 = &lB[0][0];
        gload16(gA,                       la0 + dst);
        gload16(gA + (size_t)64  * KDIM,  la0 + dst + 64  * BKB);
        gload16(gA + (size_t)128 * KDIM,  la0 + dst + 128 * BKB);
        gload16(gA + (size_t)192 * KDIM,  la0 + dst + 192 * BKB);
        gload16(gB,                       lb0 + dst);
        gload16(gB + (size_t)64  * KDIM,  lb0 + dst + 64  * BKB);
        gload16(gB + (size_t)128 * KDIM,  lb0 + dst + 128 * BKB);
        gload16(gB + (size_t)192 * KDIM,  lb0 + dst + 192 * BKB);
    }

    int32x4 acc[8][4];
#pragma unroll
    for (int i = 0; i < 8; i++)
#pragma unroll
        for (int j = 0; j < 4; j++) {
            int32x4 z = {0, 0, 0, 0};
            acc[i][j] = z;
        }

    int cur = 0;
    for (int kt = 0; kt < NKT; ++kt) {
        signed char* lAc = &lA[cur][0];
        signed char* lBc = &lB[cur][0];
        signed char* lAn = &lA[cur ^ 1][0];
        signed char* lBn = &lB[cur ^ 1][0];
        const bool pf = (kt + 1 < NKT);
        const int kb = (kt + 1) * BKB;

        int32x4 af0, af1, af2, af3, bf0, bf1, bf2, bf3;

        // ======== phase 0: stage A-half0(t+1); wait tile t; MFMA i0..3 ks0 ========
        if (pf) {
            gload16(gA + kb,                     lAn + dst);
            gload16(gA + kb + (size_t)64 * KDIM, lAn + dst + 64 * BKB);
            asm volatile("s_waitcnt vmcnt(2)" ::: "memory");
        } else {
            asm volatile("s_waitcnt vmcnt(0)" ::: "memory");
        }
        __builtin_amdgcn_s_barrier();
        __builtin_amdgcn_sched_barrier(0);
        af0 = *(const int32x4*)(lAc + arow + 0 * 2048 + ck0);
        af1 = *(const int32x4*)(lAc + arow + 1 * 2048 + ck0);
        af2 = *(const int32x4*)(lAc + arow + 2 * 2048 + ck0);
        af3 = *(const int32x4*)(lAc + arow + 3 * 2048 + ck0);
        bf0 = *(const int32x4*)(lBc + brow + 0 * 2048 + ck0);
        bf1 = *(const int32x4*)(lBc + brow + 1 * 2048 + ck0);
        bf2 = *(const int32x4*)(lBc + brow + 2 * 2048 + ck0);
        bf3 = *(const int32x4*)(lBc + brow + 3 * 2048 + ck0);
        asm volatile("s_waitcnt lgkmcnt(0)" ::: "memory");
        __builtin_amdgcn_sched_barrier(0);
        __builtin_amdgcn_s_setprio(1);
        MFMA4(0, af0) MFMA4(1, af1) MFMA4(2, af2) MFMA4(3, af3)
        __builtin_amdgcn_s_setprio(0);
        __builtin_amdgcn_s_barrier();
        __builtin_amdgcn_sched_barrier(0);

        // ======== phase 1: stage A-half1(t+1); MFMA i4..7 ks0 ========
        af0 = *(const int32x4*)(lAc + arow + 4 * 2048 + ck0);
        af1 = *(const int32x4*)(lAc + arow + 5 * 2048 + ck0);
        af2 = *(const int32x4*)(lAc + arow + 6 * 2048 + ck0);
        af3 = *(const int32x4*)(lAc + arow + 7 * 2048 + ck0);
        if (pf) {
            gload16(gA + kb + (size_t)128 * KDIM, lAn + dst + 128 * BKB);
            gload16(gA + kb + (size_t)192 * KDIM, lAn + dst + 192 * BKB);
        }
        __builtin_amdgcn_s_barrier();
        asm volatile("s_waitcnt lgkmcnt(0)" ::: "memory");
        __builtin_amdgcn_sched_barrier(0);
        __builtin_amdgcn_s_setprio(1);
        MFMA4(4, af0) MFMA4(5, af1) MFMA4(6, af2) MFMA4(7, af3)
        __builtin_amdgcn_s_setprio(0);
        __builtin_amdgcn_s_barrier();
        __builtin_amdgcn_sched_barrier(0);

        // ======== phase 2: stage B-half0(t+1); MFMA i0..3 ks1 ========
        af0 = *(const int32x4*)(lAc + arow + 0 * 2048 + ck1);
        af1 = *(const int32x4*)(lAc + arow + 1 * 2048 + ck1);
        af2 = *(const int32x4*)(lAc + arow + 2 * 2048 + ck1);
        af3 = *(const int32x4*)(lAc + arow + 3 * 2048 + ck1);
        bf0 = *(const int32x4*)(lBc + brow + 0 * 2048 + ck1);
        bf1 = *(const int32x4*)(lBc + brow + 1 * 2048 + ck1);
        bf2 = *(const int32x4*)(lBc + brow + 2 * 2048 + ck1);
        bf3 = *(const int32x4*)(lBc + brow + 3 * 2048 + ck1);
        if (pf) {
            gload16(gB + kb,                     lBn + dst);
            gload16(gB + kb + (size_t)64 * KDIM, lBn + dst + 64 * BKB);
        }
        __builtin_amdgcn_s_barrier();
        asm volatile("s_waitcnt lgkmcnt(0)" ::: "memory");
        __builtin_amdgcn_sched_barrier(0);
        __builtin_amdgcn_s_setprio(1);
        MFMA4(0, af0) MFMA4(1, af1) MFMA4(2, af2) MFMA4(3, af3)
        __builtin_amdgcn_s_setprio(0);
        __builtin_amdgcn_s_barrier();
        __builtin_amdgcn_sched_barrier(0);

        // ======== phase 3: stage B-half1(t+1); MFMA i4..7 ks1 ========
        af0 = *(const int32x4*)(lAc + arow + 4 * 2048 + ck1);
        af1 = *(const int32x4*)(lAc + arow + 5 * 2048 + ck1);
        af2 = *(const int32x4*)(lAc + arow + 6 * 2048 + ck1);
        af3 = *(const int32x4*)(lAc + arow + 7 * 2048 + ck1);
        if (pf) {
            gload16(gB + kb + (size_t)128 * KDIM, lBn + dst + 128 * BKB);
            gload16(gB + kb + (size_t)192 * KDIM, lBn + dst + 192 * BKB);
        }
        __builtin_amdgcn_s_barrier();
        asm volatile("s_waitcnt lgkmcnt(0)" ::: "memory");
        __builtin_amdgcn_sched_barrier(0);
        __builtin_amdgcn_s_setprio(1);
        MFMA4(4, af0) MFMA4(5, af1) MFMA4(6, af2) MFMA4(7, af3)
        __builtin_amdgcn_s_setprio(0);
        __builtin_amdgcn_s_barrier();
        __builtin_amdgcn_sched_barrier(0);

        cur ^= 1;
    }

    // ---- epilogue: scale + store ----
#pragma unroll
    for (int i = 0; i < 8; ++i) {
#pragma unroll
        for (int j = 0; j < 4; ++j) {
            const int ln = wn * 64 + j * 16 + lo;
            const float wsv = s_ws[ln];
            float* cp = C + (size_t)(bm * BM + wm * 128 + i * 16 + q * 4) * NDIM + bn * BN + ln;
#pragma unroll
            for (int r = 0; r < 4; ++r) {
                const int lm = wm * 128 + i * 16 + q * 4 + r;
                cp[(size_t)r * NDIM] = (float)acc[i][j][r] * s_xs[lm] * wsv;
            }
        }
    }
}

// ---------------- Kernel 3: output LayerNorm (in-place on d_out) ----------------
__global__ __launch_bounds__(256) void k_lnout(float* __restrict__ y) {
    __shared__ float sm[8];
    const int row = blockIdx.x;
    const int tid = threadIdx.x;
    float* p = y + (size_t)row * DOUT;
    float4 v0 = ((float4*)p)[tid * 2];
    float4 v1 = ((float4*)p)[tid * 2 + 1];
    float vv[8] = {v0.x, v0.y, v0.z, v0.w, v1.x, v1.y, v1.z, v1.w};
    float s = 0.f, ss = 0.f;
#pragma unroll
    for (int i = 0; i < 8; i++) { s += vv[i]; ss += vv[i] * vv[i]; }
#pragma unroll
    for (int o = 32; o; o >>= 1) { s += __shfl_down(s, o); ss += __shfl_down(ss, o); }
    const int wv = tid >> 6;
    if ((tid & 63) == 0) { sm[wv] = s; sm[4 + wv] = ss; }
    __syncthreads();
    s = sm[0] + sm[1] + sm[2] + sm[3];
    ss = sm[4] + sm[5] + sm[6] + sm[7];
    const float mu = s * (1.f / DOUT);
    const float var = ss * (1.f / DOUT) - mu * mu;
    const float rstd = 1.f / sqrtf(var + 1e-5f);
#pragma unroll
    for (int i = 0; i < 8; i++) vv[i] = (vv[i] - mu) * rstd;
    float4 o0, o1;
    o0.x = vv[0]; o0.y = vv[1]; o0.z = vv[2]; o0.w = vv[3];
    o1.x = vv[4]; o1.y = vv[5]; o1.z = vv[6]; o1.w = vv[7];
    ((float4*)p)[tid * 2] = o0;
    ((float4*)p)[tid * 2 + 1] = o1;
}

extern "C" void kernel_launch(void* const* d_in, const int* in_sizes, int n_in,
                              void* d_out, int out_size, void* d_ws, size_t ws_size,
                              hipStream_t stream) {
    const float* x = (const float*)d_in[0];
    const int* wt = (const int*)d_in[1];
    const float* wscale = (const float*)d_in[2];
    float* out = (float*)d_out;

    signed char* w8 = (signed char*)d_ws;
    signed char* xq = (signed char*)d_ws + (size_t)4 * 1024 * 1024;
    float* xs = (float*)((char*)d_ws + (size_t)36 * 1024 * 1024);

    k_wconv<<<(DOUT * DIN / 4) / 256, 256, 0, stream>>>(wt, w8);
    k_lnq<<<NTOK, 256, 0, stream>>>(x, xq, xs);
    k_gemm<<<(NTOK / BM) * (NDIM / BN), 512, 0, stream>>>(xq, w8, xs, wscale, out);
    k_lnout<<<NTOK, 256, 0, stream>>>(out);
}

// Round 3
// 164.973 us; speedup vs baseline: 1.0293x; 1.0136x over previous
//
#include <hip/hip_runtime.h>
#include <hip/hip_bf16.h>
#include <stdint.h>

using int32x4 = __attribute__((ext_vector_type(4))) int;

#define DIN 2048
#define DOUT 2048
#define NTOK 16384
#define KDIM 2048
#define NDIM 2048

#define BM 256
#define BN 256
#define BKB 128           // K-bytes (=elements) staged per tile
#define NKT (KDIM / BKB)  // 16

typedef const __attribute__((address_space(1))) void* gp_t;
typedef __attribute__((address_space(3))) void* lp_t;

__device__ __forceinline__ void gload16(const void* g, void* l) {
    __builtin_amdgcn_global_load_lds((gp_t)g, (lp_t)l, 16, 0, 0);
}

// ---------------- Kernel 0: ternary int32 -> int8 ----------------
__global__ __launch_bounds__(256) void k_wconv(const int* __restrict__ wt,
                                               signed char* __restrict__ w8) {
    int i = blockIdx.x * 256 + threadIdx.x;
    int4 v = ((const int4*)wt)[i];
    char4 c;
    c.x = (signed char)v.x; c.y = (signed char)v.y;
    c.z = (signed char)v.z; c.w = (signed char)v.w;
    ((char4*)w8)[i] = c;
}

// ---------------- Kernel 1: LayerNorm + int8 absmax quant ----------------
__global__ __launch_bounds__(256) void k_lnq(const float* __restrict__ x,
                                             signed char* __restrict__ xq,
                                             float* __restrict__ xscale) {
    __shared__ float sm[12];
    const int row = blockIdx.x;
    const int tid = threadIdx.x;
    const float* p = x + (size_t)row * DIN;
    const float4 v0 = ((const float4*)p)[tid * 2];
    const float4 v1 = ((const float4*)p)[tid * 2 + 1];
    float vv[8] = {v0.x, v0.y, v0.z, v0.w, v1.x, v1.y, v1.z, v1.w};
    float s = 0.f, ss = 0.f;
#pragma unroll
    for (int i = 0; i < 8; i++) { s += vv[i]; ss += vv[i] * vv[i]; }
#pragma unroll
    for (int o = 32; o; o >>= 1) { s += __shfl_down(s, o); ss += __shfl_down(ss, o); }
    const int wv = tid >> 6;
    if ((tid & 63) == 0) { sm[wv] = s; sm[4 + wv] = ss; }
    __syncthreads();
    s = sm[0] + sm[1] + sm[2] + sm[3];
    ss = sm[4] + sm[5] + sm[6] + sm[7];
    const float mu = s * (1.f / DIN);
    const float var = ss * (1.f / DIN) - mu * mu;
    const float rstd = 1.f / sqrtf(var + 1e-5f);
    float am = 0.f;
#pragma unroll
    for (int i = 0; i < 8; i++) am = fmaxf(am, fabsf(vv[i] - mu));
#pragma unroll
    for (int o = 32; o; o >>= 1) am = fmaxf(am, __shfl_down(am, o));
    __syncthreads();
    if ((tid & 63) == 0) sm[8 + wv] = am;
    __syncthreads();
    am = fmaxf(fmaxf(sm[8], sm[9]), fmaxf(sm[10], sm[11]));
    const float scale = fmaxf(am * rstd, 1e-5f) * (1.f / 127.f);
    union { signed char c[8]; int2 v; } u;
#pragma unroll
    for (int i = 0; i < 8; i++) {
        float xn = (vv[i] - mu) * rstd;
        float t = rintf(xn / scale);
        t = fminf(127.f, fmaxf(-127.f, t));
        u.c[i] = (signed char)t;
    }
    ((int2*)(xq + (size_t)row * DIN))[tid] = u.v;
    if (tid == 0) xscale[row] = scale;
}

// ---------------- Kernel 2: 256x256 8-phase i8 MFMA GEMM ----------------
#define MFMA4(I, AF) \
    acc[I][0] = __builtin_amdgcn_mfma_i32_16x16x64_i8(AF, b0, acc[I][0], 0, 0, 0); \
    acc[I][1] = __builtin_amdgcn_mfma_i32_16x16x64_i8(AF, b1, acc[I][1], 0, 0, 0); \
    acc[I][2] = __builtin_amdgcn_mfma_i32_16x16x64_i8(AF, b2, acc[I][2], 0, 0, 0); \
    acc[I][3] = __builtin_amdgcn_mfma_i32_16x16x64_i8(AF, b3, acc[I][3], 0, 0, 0);

#define SCHED __builtin_amdgcn_sched_barrier(0);
#define BAR   __builtin_amdgcn_s_barrier();
#define LGKM0 asm volatile("s_waitcnt lgkmcnt(0)" ::: "memory");
#define VM0   asm volatile("s_waitcnt vmcnt(0)" ::: "memory");

__global__ __launch_bounds__(512, 2) void k_gemm(const signed char* __restrict__ A,
                                                 const signed char* __restrict__ B,
                                                 const float* __restrict__ xs,
                                                 const float* __restrict__ wsc,
                                                 float* __restrict__ C) {
    __shared__ __align__(16) signed char lA[2][BM * BKB];  // 64 KB
    __shared__ __align__(16) signed char lB[2][BN * BKB];  // 64 KB
    __shared__ float s_xs[BM];
    __shared__ float s_ws[BN];

    const int tid = threadIdx.x;
    const int orig = blockIdx.x;
    const int bid = (orig & 7) * 64 + (orig >> 3);  // 512 % 8 == 0 -> bijective
    const int bm = bid >> 3;   // 0..63
    const int bn = bid & 7;    // 0..7

    const int lane = tid & 63;
    const int wave = tid >> 6;
    const int wm = wave >> 2;  // 0..1
    const int wn = wave & 3;   // 0..3
    const int lo = lane & 15;
    const int q  = lane >> 4;

    // staging geometry: LDS (row r, chunk c) holds global k-chunk (c ^ (r&7))
    const int srow = tid >> 3;
    const int schunk = tid & 7;
    const int gchunk = schunk ^ (srow & 7);
    const signed char* gA = A + (size_t)(bm * BM + srow) * KDIM + gchunk * 16;
    const signed char* gB = B + (size_t)(bn * BN + srow) * KDIM + gchunk * 16;
    const int dst = srow * BKB + schunk * 16;

    // fragment read offsets (swizzled)
    const int arow = (wm * 128 + lo) * BKB;
    const int brow = (wn * 64 + lo) * BKB;
    const int ck0 = (q ^ (lane & 7)) * 16;
    const int ck1 = ((4 + q) ^ (lane & 7)) * 16;

    if (tid < 256) s_xs[tid] = xs[bm * BM + tid];
    else           s_ws[tid - 256] = wsc[bn * BN + tid - 256];

    // ---- prologue: stage tile 0 into buf 0 ----
    {
        signed char* la0 = &lA[0][0];
        signed char* lb0 = &lB[0][0];
        gload16(gA,                       la0 + dst);
        gload16(gA + (size_t)64  * KDIM,  la0 + dst + 64  * BKB);
        gload16(gA + (size_t)128 * KDIM,  la0 + dst + 128 * BKB);
        gload16(gA + (size_t)192 * KDIM,  la0 + dst + 192 * BKB);
        gload16(gB,                       lb0 + dst);
        gload16(gB + (size_t)64  * KDIM,  lb0 + dst + 64  * BKB);
        gload16(gB + (size_t)128 * KDIM,  lb0 + dst + 128 * BKB);
        gload16(gB + (size_t)192 * KDIM,  lb0 + dst + 192 * BKB);
    }
    VM0 SCHED BAR SCHED

    int32x4 acc[8][4];
#pragma unroll
    for (int i = 0; i < 8; i++)
#pragma unroll
        for (int j = 0; j < 4; j++) {
            int32x4 z = {0, 0, 0, 0};
            acc[i][j] = z;
        }

    for (int kt = 0; kt < NKT; ++kt) {
        signed char* lAc = &lA[kt & 1][0];
        signed char* lBc = &lB[kt & 1][0];
        signed char* lAn = &lA[(kt & 1) ^ 1][0];
        signed char* lBn = &lB[(kt & 1) ^ 1][0];
        const bool pf = (kt + 1 < NKT);
        const int kb = (kt + 1) * BKB;
        int32x4 a0, a1, a2, a3, b0, b1, b2, b3;

        // ===== phase 0: [reads A i0-3 ks0 + B ks0 | stage A(t+1)] bar; MFMA =====
        a0 = *(const int32x4*)(lAc + arow + 0 * 2048 + ck0);
        a1 = *(const int32x4*)(lAc + arow + 1 * 2048 + ck0);
        a2 = *(const int32x4*)(lAc + arow + 2 * 2048 + ck0);
        a3 = *(const int32x4*)(lAc + arow + 3 * 2048 + ck0);
        b0 = *(const int32x4*)(lBc + brow + 0 * 2048 + ck0);
        b1 = *(const int32x4*)(lBc + brow + 1 * 2048 + ck0);
        b2 = *(const int32x4*)(lBc + brow + 2 * 2048 + ck0);
        b3 = *(const int32x4*)(lBc + brow + 3 * 2048 + ck0);
        if (pf) {
            gload16(gA + kb,                      lAn + dst);
            gload16(gA + kb + (size_t)64  * KDIM, lAn + dst + 64  * BKB);
            gload16(gA + kb + (size_t)128 * KDIM, lAn + dst + 128 * BKB);
            gload16(gA + kb + (size_t)192 * KDIM, lAn + dst + 192 * BKB);
        }
        SCHED BAR LGKM0 SCHED
        __builtin_amdgcn_s_setprio(1);
        MFMA4(0, a0) MFMA4(1, a1) MFMA4(2, a2) MFMA4(3, a3)
        __builtin_amdgcn_s_setprio(0);
        SCHED BAR SCHED

        // ===== phase 1: [reads A i4-7 ks0 | stage B(t+1)] bar; MFMA =====
        a0 = *(const int32x4*)(lAc + arow + 4 * 2048 + ck0);
        a1 = *(const int32x4*)(lAc + arow + 5 * 2048 + ck0);
        a2 = *(const int32x4*)(lAc + arow + 6 * 2048 + ck0);
        a3 = *(const int32x4*)(lAc + arow + 7 * 2048 + ck0);
        if (pf) {
            gload16(gB + kb,                      lBn + dst);
            gload16(gB + kb + (size_t)64  * KDIM, lBn + dst + 64  * BKB);
            gload16(gB + kb + (size_t)128 * KDIM, lBn + dst + 128 * BKB);
            gload16(gB + kb + (size_t)192 * KDIM, lBn + dst + 192 * BKB);
        }
        SCHED BAR LGKM0 SCHED
        __builtin_amdgcn_s_setprio(1);
        MFMA4(4, a0) MFMA4(5, a1) MFMA4(6, a2) MFMA4(7, a3)
        __builtin_amdgcn_s_setprio(0);
        SCHED BAR SCHED

        // ===== phase 2: [reads A i0-3 ks1 + B ks1] bar; MFMA =====
        a0 = *(const int32x4*)(lAc + arow + 0 * 2048 + ck1);
        a1 = *(const int32x4*)(lAc + arow + 1 * 2048 + ck1);
        a2 = *(const int32x4*)(lAc + arow + 2 * 2048 + ck1);
        a3 = *(const int32x4*)(lAc + arow + 3 * 2048 + ck1);
        b0 = *(const int32x4*)(lBc + brow + 0 * 2048 + ck1);
        b1 = *(const int32x4*)(lBc + brow + 1 * 2048 + ck1);
        b2 = *(const int32x4*)(lBc + brow + 2 * 2048 + ck1);
        b3 = *(const int32x4*)(lBc + brow + 3 * 2048 + ck1);
        SCHED BAR LGKM0 SCHED
        __builtin_amdgcn_s_setprio(1);
        MFMA4(0, a0) MFMA4(1, a1) MFMA4(2, a2) MFMA4(3, a3)
        __builtin_amdgcn_s_setprio(0);
        SCHED BAR SCHED

        // ===== phase 3: [reads A i4-7 ks1] bar; MFMA; vmcnt-drain =====
        a0 = *(const int32x4*)(lAc + arow + 4 * 2048 + ck1);
        a1 = *(const int32x4*)(lAc + arow + 5 * 2048 + ck1);
        a2 = *(const int32x4*)(lAc + arow + 6 * 2048 + ck1);
        a3 = *(const int32x4*)(lAc + arow + 7 * 2048 + ck1);
        SCHED BAR LGKM0 SCHED
        __builtin_amdgcn_s_setprio(1);
        MFMA4(4, a0) MFMA4(5, a1) MFMA4(6, a2) MFMA4(7, a3)
        __builtin_amdgcn_s_setprio(0);
        VM0 SCHED BAR SCHED   // tile t+1 fully staged (issued ~3 phases ago)
    }

    // ---- epilogue: scale + store ----
#pragma unroll
    for (int i = 0; i < 8; ++i) {
#pragma unroll
        for (int j = 0; j < 4; ++j) {
            const int ln = wn * 64 + j * 16 + lo;
            const float wsv = s_ws[ln];
            float* cp = C + (size_t)(bm * BM + wm * 128 + i * 16 + q * 4) * NDIM + bn * BN + ln;
#pragma unroll
            for (int r = 0; r < 4; ++r) {
                const int lm = wm * 128 + i * 16 + q * 4 + r;
                cp[(size_t)r * NDIM] = (float)acc[i][j][r] * s_xs[lm] * wsv;
            }
        }
    }
}

// ---------------- Kernel 3: output LayerNorm (in-place on d_out) ----------------
__global__ __launch_bounds__(256) void k_lnout(float* __restrict__ y) {
    __shared__ float sm[8];
    const int row = blockIdx.x;
    const int tid = threadIdx.x;
    float* p = y + (size_t)row * DOUT;
    float4 v0 = ((float4*)p)[tid * 2];
    float4 v1 = ((float4*)p)[tid * 2 + 1];
    float vv[8] = {v0.x, v0.y, v0.z, v0.w, v1.x, v1.y, v1.z, v1.w};
    float s = 0.f, ss = 0.f;
#pragma unroll
    for (int i = 0; i < 8; i++) { s += vv[i]; ss += vv[i] * vv[i]; }
#pragma unroll
    for (int o = 32; o; o >>= 1) { s += __shfl_down(s, o); ss += __shfl_down(ss, o); }
    const int wv = tid >> 6;
    if ((tid & 63) == 0) { sm[wv] = s; sm[4 + wv] = ss; }
    __syncthreads();
    s = sm[0] + sm[1] + sm[2] + sm[3];
    ss = sm[4] + sm[5] + sm[6] + sm[7];
    const float mu = s * (1.f / DOUT);
    const float var = ss * (1.f / DOUT) - mu * mu;
    const float rstd = 1.f / sqrtf(var + 1e-5f);
#pragma unroll
    for (int i = 0; i < 8; i++) vv[i] = (vv[i] - mu) * rstd;
    float4 o0, o1;
    o0.x = vv[0]; o0.y = vv[1]; o0.z = vv[2]; o0.w = vv[3];
    o1.x = vv[4]; o1.y = vv[5]; o1.z = vv[6]; o1.w = vv[7];
    ((float4*)p)[tid * 2] = o0;
    ((float4*)p)[tid * 2 + 1] = o1;
}

extern "C" void kernel_launch(void* const* d_in, const int* in_sizes, int n_in,
                              void* d_out, int out_size, void* d_ws, size_t ws_size,
                              hipStream_t stream) {
    const float* x = (const float*)d_in[0];
    const int* wt = (const int*)d_in[1];
    const float* wscale = (const float*)d_in[2];
    float* out = (float*)d_out;

    signed char* w8 = (signed char*)d_ws;
    signed char* xq = (signed char*)d_ws + (size_t)4 * 1024 * 1024;
    float* xs = (float*)((char*)d_ws + (size_t)36 * 1024 * 1024);

    k_wconv<<<(DOUT * DIN / 4) / 256, 256, 0, stream>>>(wt, w8);
    k_lnq<<<NTOK, 256, 0, stream>>>(x, xq, xs);
    k_gemm<<<(NTOK / BM) * (NDIM / BN), 512, 0, stream>>>(xq, w8, xs, wscale, out);
    k_lnout<<<NTOK, 256, 0, stream>>>(out);
}

// Round 4
// 157.892 us; speedup vs baseline: 1.0755x; 1.0448x over previous
//
#include <hip/hip_runtime.h>
#include <hip/hip_bf16.h>
#include <stdint.h>

using int32x4 = __attribute__((ext_vector_type(4))) int;

#define DIN 2048
#define DOUT 2048
#define NTOK 16384
#define KDIM 2048
#define NDIM 2048

#define BM 256
#define BN 256
#define BKB 64            // K-bytes per tile
#define NKT (KDIM / BKB)  // 32
#define TILEB (BM * BKB)  // 16384 bytes per matrix per tile

typedef const __attribute__((address_space(1))) void* gp_t;
typedef __attribute__((address_space(3))) void* lp_t;

__device__ __forceinline__ void gload16(const void* g, void* l) {
    __builtin_amdgcn_global_load_lds((gp_t)g, (lp_t)l, 16, 0, 0);
}

// ---------------- Kernel 0: ternary int32 -> int8 ----------------
__global__ __launch_bounds__(256) void k_wconv(const int* __restrict__ wt,
                                               signed char* __restrict__ w8) {
    int i = blockIdx.x * 256 + threadIdx.x;
    int4 v = ((const int4*)wt)[i];
    char4 c;
    c.x = (signed char)v.x; c.y = (signed char)v.y;
    c.z = (signed char)v.z; c.w = (signed char)v.w;
    ((char4*)w8)[i] = c;
}

// ---------------- Kernel 1: LayerNorm + int8 absmax quant ----------------
__global__ __launch_bounds__(256) void k_lnq(const float* __restrict__ x,
                                             signed char* __restrict__ xq,
                                             float* __restrict__ xscale) {
    __shared__ float sm[12];
    const int row = blockIdx.x;
    const int tid = threadIdx.x;
    const float* p = x + (size_t)row * DIN;
    const float4 v0 = ((const float4*)p)[tid * 2];
    const float4 v1 = ((const float4*)p)[tid * 2 + 1];
    float vv[8] = {v0.x, v0.y, v0.z, v0.w, v1.x, v1.y, v1.z, v1.w};
    float s = 0.f, ss = 0.f;
#pragma unroll
    for (int i = 0; i < 8; i++) { s += vv[i]; ss += vv[i] * vv[i]; }
#pragma unroll
    for (int o = 32; o; o >>= 1) { s += __shfl_down(s, o); ss += __shfl_down(ss, o); }
    const int wv = tid >> 6;
    if ((tid & 63) == 0) { sm[wv] = s; sm[4 + wv] = ss; }
    __syncthreads();
    s = sm[0] + sm[1] + sm[2] + sm[3];
    ss = sm[4] + sm[5] + sm[6] + sm[7];
    const float mu = s * (1.f / DIN);
    const float var = ss * (1.f / DIN) - mu * mu;
    const float rstd = 1.f / sqrtf(var + 1e-5f);
    float am = 0.f;
#pragma unroll
    for (int i = 0; i < 8; i++) am = fmaxf(am, fabsf(vv[i] - mu));
#pragma unroll
    for (int o = 32; o; o >>= 1) am = fmaxf(am, __shfl_down(am, o));
    __syncthreads();
    if ((tid & 63) == 0) sm[8 + wv] = am;
    __syncthreads();
    am = fmaxf(fmaxf(sm[8], sm[9]), fmaxf(sm[10], sm[11]));
    const float scale = fmaxf(am * rstd, 1e-5f) * (1.f / 127.f);
    union { signed char c[8]; int2 v; } u;
#pragma unroll
    for (int i = 0; i < 8; i++) {
        float xn = (vv[i] - mu) * rstd;
        float t = rintf(xn / scale);
        t = fminf(127.f, fmaxf(-127.f, t));
        u.c[i] = (signed char)t;
    }
    ((int2*)(xq + (size_t)row * DIN))[tid] = u.v;
    if (tid == 0) xscale[row] = scale;
}

// ---------------- Kernel 2: 256x256 triple-buffer counted-vmcnt i8 GEMM ----------------
#define MFMA4(I, AF) \
    acc[I][0] = __builtin_amdgcn_mfma_i32_16x16x64_i8(AF, b0, acc[I][0], 0, 0, 0); \
    acc[I][1] = __builtin_amdgcn_mfma_i32_16x16x64_i8(AF, b1, acc[I][1], 0, 0, 0); \
    acc[I][2] = __builtin_amdgcn_mfma_i32_16x16x64_i8(AF, b2, acc[I][2], 0, 0, 0); \
    acc[I][3] = __builtin_amdgcn_mfma_i32_16x16x64_i8(AF, b3, acc[I][3], 0, 0, 0);

#define SCHED __builtin_amdgcn_sched_barrier(0);
#define BAR   __builtin_amdgcn_s_barrier();

__global__ __launch_bounds__(512, 2) void k_gemm(const signed char* __restrict__ A,
                                                 const signed char* __restrict__ B,
                                                 const float* __restrict__ xs,
                                                 const float* __restrict__ wsc,
                                                 float* __restrict__ C) {
    __shared__ __align__(16) signed char lA[3][TILEB];  // 48 KB
    __shared__ __align__(16) signed char lB[3][TILEB];  // 48 KB
    __shared__ float s_xs[BM];
    __shared__ float s_ws[BN];

    const int tid = threadIdx.x;
    const int orig = blockIdx.x;
    const int bid = (orig & 7) * 64 + (orig >> 3);  // 512 % 8 == 0 -> bijective
    const int bm = bid >> 3;   // 0..63
    const int bn = bid & 7;    // 0..7

    const int lane = tid & 63;
    const int wave = tid >> 6;
    const int wm = wave >> 2;  // 0..1
    const int wn = wave & 3;   // 0..3
    const int lo = lane & 15;
    const int q  = lane >> 4;

    // ---- staging geometry ----
    // LDS slot (row r, slot s) holds global chunk s ^ ((r>>1)&3); dst = tid*16 (linear).
    const int srow = tid >> 2;                       // 0..127
    const int gch  = (tid & 3) ^ ((srow >> 1) & 3);
    const signed char* gA = A + (size_t)(bm * BM + srow) * KDIM + gch * 16;
    const signed char* gB = B + (size_t)(bn * BN + srow) * KDIM + gch * 16;
    const int dst = tid * 16;

    // ---- fragment read bases (slot constant per thread; i-offsets compile-time) ----
    const int slot = (q ^ ((lo >> 1) & 3)) * 16;
    const int abase = (wm * 128 + lo) * BKB + slot;
    const int bbase = (wn * 64 + lo) * BKB + slot;

    if (tid < 256) s_xs[tid] = xs[bm * BM + tid];
    else           s_ws[tid - 256] = wsc[bn * BN + tid - 256];

#define STAGE_A(T, BUF) \
    gload16(gA + (T) * BKB,                        &lA[BUF][0] + dst); \
    gload16(gA + (T) * BKB + (size_t)128 * KDIM,   &lA[BUF][0] + dst + 8192);
#define STAGE_B(T, BUF) \
    gload16(gB + (T) * BKB,                        &lB[BUF][0] + dst); \
    gload16(gB + (T) * BKB + (size_t)128 * KDIM,   &lB[BUF][0] + dst + 8192);

    // ---- prologue: stage tiles 0,1 ----
    STAGE_A(0, 0) STAGE_B(0, 0)
    STAGE_A(1, 1) STAGE_B(1, 1)
    asm volatile("s_waitcnt vmcnt(0)" ::: "memory");
    SCHED BAR SCHED

    int32x4 acc[8][4];
#pragma unroll
    for (int i = 0; i < 8; i++)
#pragma unroll
        for (int j = 0; j < 4; j++) {
            int32x4 z = {0, 0, 0, 0};
            acc[i][j] = z;
        }

    int cur = 0, nx2 = 2;
    for (int t = 0; t < NKT; ++t) {
        const signed char* lAc = &lA[cur][0];
        const signed char* lBc = &lB[cur][0];
        int32x4 a0, a1, a2, a3, a4, a5, a6, a7, b0, b1, b2, b3;

        // loop-top: issue ALL reads for tile t (buffer ready since tile t-1's barrier)
        a0 = *(const int32x4*)(lAc + abase + 0 * 1024);
        a1 = *(const int32x4*)(lAc + abase + 1 * 1024);
        a2 = *(const int32x4*)(lAc + abase + 2 * 1024);
        a3 = *(const int32x4*)(lAc + abase + 3 * 1024);
        b0 = *(const int32x4*)(lBc + bbase + 0 * 1024);
        b1 = *(const int32x4*)(lBc + bbase + 1 * 1024);
        b2 = *(const int32x4*)(lBc + bbase + 2 * 1024);
        b3 = *(const int32x4*)(lBc + bbase + 3 * 1024);
        a4 = *(const int32x4*)(lAc + abase + 4 * 1024);
        a5 = *(const int32x4*)(lAc + abase + 5 * 1024);
        a6 = *(const int32x4*)(lAc + abase + 6 * 1024);
        a7 = *(const int32x4*)(lAc + abase + 7 * 1024);
        // tile t+1 landed (its loads were issued 2 tiles ago; nothing younger in flight)
        asm volatile("s_waitcnt vmcnt(0)" ::: "memory");
        SCHED
        BAR   // after: t+1 globally ready; everyone done reading t-1 -> its buffer reusable
        SCHED
        if (t + 2 < NKT) {   // stage tile t+2 into buffer (t+2)%3 (= (t-1)%3)
            STAGE_A(t + 2, nx2)
            STAGE_B(t + 2, nx2)
        }
        SCHED
        asm volatile("s_waitcnt lgkmcnt(4)" ::: "memory");  // a0-3,b0-3 ready
        SCHED
        __builtin_amdgcn_s_setprio(1);
        MFMA4(0, a0) MFMA4(1, a1) MFMA4(2, a2) MFMA4(3, a3)
        __builtin_amdgcn_s_setprio(0);
        SCHED
        asm volatile("s_waitcnt lgkmcnt(0)" ::: "memory");  // a4-7 ready
        SCHED
        __builtin_amdgcn_s_setprio(1);
        MFMA4(4, a4) MFMA4(5, a5) MFMA4(6, a6) MFMA4(7, a7)
        __builtin_amdgcn_s_setprio(0);
        SCHED

        cur = (cur == 2) ? 0 : cur + 1;
        nx2 = (nx2 == 2) ? 0 : nx2 + 1;
    }

    // ---- epilogue: scale + store ----
#pragma unroll
    for (int i = 0; i < 8; ++i) {
#pragma unroll
        for (int j = 0; j < 4; ++j) {
            const int ln = wn * 64 + j * 16 + lo;
            const float wsv = s_ws[ln];
            float* cp = C + (size_t)(bm * BM + wm * 128 + i * 16 + q * 4) * NDIM + bn * BN + ln;
#pragma unroll
            for (int r = 0; r < 4; ++r) {
                const int lm = wm * 128 + i * 16 + q * 4 + r;
                cp[(size_t)r * NDIM] = (float)acc[i][j][r] * s_xs[lm] * wsv;
            }
        }
    }
}

// ---------------- Kernel 3: output LayerNorm (in-place on d_out) ----------------
__global__ __launch_bounds__(256) void k_lnout(float* __restrict__ y) {
    __shared__ float sm[8];
    const int row = blockIdx.x;
    const int tid = threadIdx.x;
    float* p = y + (size_t)row * DOUT;
    float4 v0 = ((float4*)p)[tid * 2];
    float4 v1 = ((float4*)p)[tid * 2 + 1];
    float vv[8] = {v0.x, v0.y, v0.z, v0.w, v1.x, v1.y, v1.z, v1.w};
    float s = 0.f, ss = 0.f;
#pragma unroll
    for (int i = 0; i < 8; i++) { s += vv[i]; ss += vv[i] * vv[i]; }
#pragma unroll
    for (int o = 32; o; o >>= 1) { s += __shfl_down(s, o); ss += __shfl_down(ss, o); }
    const int wv = tid >> 6;
    if ((tid & 63) == 0) { sm[wv] = s; sm[4 + wv] = ss; }
    __syncthreads();
    s = sm[0] + sm[1] + sm[2] + sm[3];
    ss = sm[4] + sm[5] + sm[6] + sm[7];
    const float mu = s * (1.f / DOUT);
    const float var = ss * (1.f / DOUT) - mu * mu;
    const float rstd = 1.f / sqrtf(var + 1e-5f);
#pragma unroll
    for (int i = 0; i < 8; i++) vv[i] = (vv[i] - mu) * rstd;
    float4 o0, o1;
    o0.x = vv[0]; o0.y = vv[1]; o0.z = vv[2]; o0.w = vv[3];
    o1.x = vv[4]; o1.y = vv[5]; o1.z = vv[6]; o1.w = vv[7];
    ((float4*)p)[tid * 2] = o0;
    ((float4*)p)[tid * 2 + 1] = o1;
}

extern "C" void kernel_launch(void* const* d_in, const int* in_sizes, int n_in,
                              void* d_out, int out_size, void* d_ws, size_t ws_size,
                              hipStream_t stream) {
    const float* x = (const float*)d_in[0];
    const int* wt = (const int*)d_in[1];
    const float* wscale = (const float*)d_in[2];
    float* out = (float*)d_out;

    signed char* w8 = (signed char*)d_ws;
    signed char* xq = (signed char*)d_ws + (size_t)4 * 1024 * 1024;
    float* xs = (float*)((char*)d_ws + (size_t)36 * 1024 * 1024);

    k_wconv<<<(DOUT * DIN / 4) / 256, 256, 0, stream>>>(wt, w8);
    k_lnq<<<NTOK, 256, 0, stream>>>(x, xq, xs);
    k_gemm<<<(NTOK / BM) * (NDIM / BN), 512, 0, stream>>>(xq, w8, xs, wscale, out);
    k_lnout<<<NTOK, 256, 0, stream>>>(out);
}